// Round 3
// baseline (155.352 us; speedup 1.0000x reference)
//
#include <hip/hip_runtime.h>
#include <stdint.h>

// Problem constants (fixed by reference setup_inputs)
#define N_NODES 8192
#define F_IN    256
#define F_OUT   64
#define N_EDGES 262144
#define LEAKY   0.2f
#define BN_EPSF 1e-5f
#define WPR     256            // bitmap words per row = N_NODES/32
#define MAXDEG  256            // Poisson(32): max row degree ~66; 256 is 8-sigma safe
#define WT_LD   260            // Wt leading dim: 4 mod 32 -> conflict-free b128 phases

typedef unsigned int u32;

__device__ __forceinline__ float lrelu(float x) {
    return fmaxf(x, LEAKY * x);   // slope in (0,1): monotone increasing
}

// K1: hp = h @ W (8192x256x64), f1 = hp@a1, f2 = hp@a2.
// Grid = 256 blocks (1/CU). Block: 32 rows, 8 rows per wave.
// W transposed into LDS once per CU; inner loop is b128 LDS reads only.
__global__ __launch_bounds__(256) void k_hp(
    const float* __restrict__ h, const float* __restrict__ W, const float* __restrict__ a,
    float* __restrict__ hp, float* __restrict__ f1, float* __restrict__ f2)
{
    __shared__ float Wt[F_OUT * WT_LD];   // 66,560 B (transposed, padded)
    __shared__ float hl[32 * F_IN];       // 32,768 B
    const int tid = threadIdx.x;

    // Transpose W[k][o] -> Wt[o][k]. Global b32 coalesced; LDS 8-way write
    // conflict is a one-time ~2K-cycle cost per CU.
#pragma unroll
    for (int i = tid; i < F_IN * F_OUT; i += 256)
        Wt[(i & 63) * WT_LD + (i >> 6)] = W[i];

    // Stage 32 rows of h (float4 coalesced)
    const int row0 = blockIdx.x * 32;
    float4* hl4 = reinterpret_cast<float4*>(hl);
    const float4* h4 = reinterpret_cast<const float4*>(h + (size_t)row0 * F_IN);
#pragma unroll
    for (int p = 0; p < 8; ++p)
        hl4[tid + p * 256] = h4[tid + p * 256];
    __syncthreads();

    const int w = tid >> 6, o = tid & 63;
    const int rbase = w * 8;              // 8 rows per wave
    float acc[8] = {0.f, 0.f, 0.f, 0.f, 0.f, 0.f, 0.f, 0.f};

    for (int q = 0; q < 64; ++q) {
        const float4 wv = *reinterpret_cast<const float4*>(&Wt[o * WT_LD + 4 * q]);
#pragma unroll
        for (int r = 0; r < 8; ++r) {
            const float4 hv = *reinterpret_cast<const float4*>(&hl[(rbase + r) * F_IN + 4 * q]);
            acc[r] += wv.x * hv.x + wv.y * hv.y + wv.z * hv.z + wv.w * hv.w;
        }
    }

    const float a1 = a[o], a2 = a[F_OUT + o];
#pragma unroll
    for (int r = 0; r < 8; ++r) {
        const int row = row0 + rbase + r;
        hp[row * F_OUT + o] = acc[r];
        float p1 = acc[r] * a1;
        float p2 = acc[r] * a2;
#pragma unroll
        for (int off = 32; off; off >>= 1) {
            p1 += __shfl_xor(p1, off, 64);
            p2 += __shfl_xor(p2, off, 64);
        }
        if (o == 0) { f1[row] = p1; f2[row] = p2; }
    }
}

// K2: adjacency bitmap (dedups duplicate edges, same as boolean adj in ref)
__global__ __launch_bounds__(256) void k_adj(const int* __restrict__ ei, u32* __restrict__ bm)
{
    const int e = blockIdx.x * 256 + threadIdx.x;
    const int r = ei[e];
    const int c = ei[N_EDGES + e];
    atomicOr(&bm[(size_t)r * WPR + (c >> 5)], 1u << (c & 31));
}

// K3: one ROW per block (4 waves). Bitmap -> compact neighbor list -> row max
// -> softmax denom + weighted hp gather, neighbors split across the 4 waves.
__global__ __launch_bounds__(256) void k_attn(
    const u32* __restrict__ bm, const float* __restrict__ hp,
    const float* __restrict__ f1g, const float* __restrict__ f2g,
    float* __restrict__ Mg, float* __restrict__ Dg, float* __restrict__ outr)
{
    __shared__ int   nbr[MAXDEG];
    __shared__ float fv [MAXDEG];
    __shared__ int   cnt;
    __shared__ float redm[4];
    __shared__ float accs[4][F_OUT];
    __shared__ float dens[4];
    const int tid = threadIdx.x;
    const int w = tid >> 6, lane = tid & 63;
    const int row = blockIdx.x;
    if (tid == 0) cnt = 0;
    __syncthreads();

    // Extraction: thread t scans bitmap word t
    u32 bits = bm[(size_t)row * WPR + tid];
    float mymax = -1e30f;
    if (bits) {
        int pos = atomicAdd(&cnt, __popc(bits));
        while (bits) {
            const int b = __ffs(bits) - 1;
            bits &= bits - 1;
            const int j = tid * 32 + b;
            const float v = f2g[j];
            mymax = fmaxf(mymax, v);
            if (pos < MAXDEG) { nbr[pos] = j; fv[pos] = v; }
            ++pos;
        }
    }
#pragma unroll
    for (int off = 32; off; off >>= 1)
        mymax = fmaxf(mymax, __shfl_xor(mymax, off, 64));
    if (lane == 0) redm[w] = mymax;
    __syncthreads();

    const int deg = min(cnt, MAXDEG);
    const float f1i = f1g[row];
    const float M = lrelu(f1i + fmaxf(fmaxf(redm[0], redm[1]), fmaxf(redm[2], redm[3])));

    float den = 0.f, acc = 0.f;
    for (int n = w; n < deg; n += 4) {
        const int j = nbr[n];
        const float wgt = __expf(lrelu(f1i + fv[n]) - M);
        den += wgt;
        acc += wgt * hp[j * F_OUT + lane];   // 256B coalesced gather per wave
    }
    accs[w][lane] = acc;                     // bank = lane&31: 2-way, free
    if (lane == 0) dens[w] = den;
    __syncthreads();

    if (w == 0) {
        float av = accs[0][lane] + accs[1][lane] + accs[2][lane] + accs[3][lane];
        float d = dens[0] + dens[1] + dens[2] + dens[3];
        float Mw = M;
        if (deg == 0) { d = 1.f; Mw = 0.f; av = 0.f; }  // degenerate guard
        outr[row * F_OUT + lane] = av / d;
        if (lane == 0) { Mg[row] = Mw; Dg[row] = d; }
    }
}

// K4: BN partial sums (coalesced float4), atomicAdd into zeroed Sacc/Qacc[64]
__global__ __launch_bounds__(256) void k_bnpart(
    const float* __restrict__ outr, float* __restrict__ Sacc, float* __restrict__ Qacc)
{
    __shared__ float4 sp[16][16], sq[16][16];
    const int tid = threadIdx.x;
    const int m = tid >> 4, f4 = tid & 15;
    const float4* o4 = reinterpret_cast<const float4*>(outr);
    float4 s = {0.f, 0.f, 0.f, 0.f}, q = {0.f, 0.f, 0.f, 0.f};
#pragma unroll
    for (int p = 0; p < 2; ++p) {
        const float4 v = o4[blockIdx.x * 512 + tid + p * 256];
        s.x += v.x; s.y += v.y; s.z += v.z; s.w += v.w;
        q.x += v.x * v.x; q.y += v.y * v.y; q.z += v.z * v.z; q.w += v.w * v.w;
    }
    sp[m][f4] = s; sq[m][f4] = q;
    for (int st = 8; st; st >>= 1) {
        __syncthreads();
        if (m < st) {
            float4 xs = sp[m + st][f4], xq = sq[m + st][f4];
            float4 cs = sp[m][f4], cq = sq[m][f4];
            cs.x += xs.x; cs.y += xs.y; cs.z += xs.z; cs.w += xs.w;
            cq.x += xq.x; cq.y += xq.y; cq.z += xq.z; cq.w += xq.w;
            sp[m][f4] = cs; sq[m][f4] = cq;
        }
    }
    __syncthreads();
    if (tid < 16) {
        const float4 cs = sp[0][tid], cq = sq[0][tid];
        atomicAdd(&Sacc[tid * 4 + 0], cs.x); atomicAdd(&Sacc[tid * 4 + 1], cs.y);
        atomicAdd(&Sacc[tid * 4 + 2], cs.z); atomicAdd(&Sacc[tid * 4 + 3], cs.w);
        atomicAdd(&Qacc[tid * 4 + 0], cq.x); atomicAdd(&Qacc[tid * 4 + 1], cq.y);
        atomicAdd(&Qacc[tid * 4 + 2], cq.z); atomicAdd(&Qacc[tid * 4 + 3], cq.w);
    }
}

// K5: BN finalize + apply + bias (mean/rstd recomputed per thread from Sacc/Qacc)
__global__ __launch_bounds__(256) void k_bnapply(
    const float* __restrict__ outr, const float* __restrict__ Sacc,
    const float* __restrict__ Qacc, const float* __restrict__ gamma,
    const float* __restrict__ beta, const float* __restrict__ bias,
    float* __restrict__ out)
{
    const int idx = blockIdx.x * 256 + threadIdx.x;
    const int o = idx & 63;
    const float mean = Sacc[o] * (1.f / N_NODES);
    const float var = Qacc[o] * (1.f / N_NODES) - mean * mean;
    const float rstd = rsqrtf(var + BN_EPSF);
    out[idx] = (outr[idx] - mean) * rstd * gamma[o] + beta[o] + bias[o];
}

// K6: alpha[e] = att[row[e], col[e]]
__global__ __launch_bounds__(256) void k_alpha(
    const int* __restrict__ ei, const float* __restrict__ f1g,
    const float* __restrict__ f2g, const float* __restrict__ Mg,
    const float* __restrict__ Dg, float* __restrict__ out)
{
    const int e = blockIdx.x * 256 + threadIdx.x;
    const int r = ei[e];
    const int c = ei[N_EDGES + e];
    out[N_NODES * F_OUT + e] = __expf(lrelu(f1g[r] + f2g[c]) - Mg[r]) / Dg[r];
}

extern "C" void kernel_launch(void* const* d_in, const int* in_sizes, int n_in,
                              void* d_out, int out_size, void* d_ws, size_t ws_size,
                              hipStream_t stream) {
    const float* h     = (const float*)d_in[0];
    const int*   ei    = (const int*)  d_in[1];
    const float* W     = (const float*)d_in[2];
    const float* a     = (const float*)d_in[3];
    const float* bias  = (const float*)d_in[4];
    const float* gamma = (const float*)d_in[5];
    const float* beta  = (const float*)d_in[6];
    float* out = (float*)d_out;

    char* ws = (char*)d_ws;
    float* hp    = (float*)(ws + 0);          // 2 MB
    float* f1    = (float*)(ws + 2097152);    // 32 KB
    float* f2    = (float*)(ws + 2129920);    // 32 KB
    float* Mg    = (float*)(ws + 2162688);    // 32 KB
    float* Dg    = (float*)(ws + 2195456);    // 32 KB
    float* outr  = (float*)(ws + 2228224);    // 2 MB
    float* Sacc  = (float*)(ws + 4325376);    // 256 B  } zeroed together
    float* Qacc  = (float*)(ws + 4325632);    // 256 B  } with bm below
    u32*   bm    = (u32*)  (ws + 4325888);    // 8 MB
    if (ws_size < (size_t)4325888 + (size_t)N_NODES * WPR * 4) return;

    // One memset covers Sacc+Qacc (512B) and the bitmap (8MB)
    hipMemsetAsync(ws + 4325376, 0, 512 + (size_t)N_NODES * WPR * 4, stream);
    k_hp     <<<N_NODES / 32, 256, 0, stream>>>(h, W, a, hp, f1, f2);
    k_adj    <<<N_EDGES / 256, 256, 0, stream>>>(ei, bm);
    k_attn   <<<N_NODES, 256, 0, stream>>>(bm, hp, f1, f2, Mg, Dg, outr);
    k_bnpart <<<N_NODES / 32, 256, 0, stream>>>(outr, Sacc, Qacc);
    k_bnapply<<<(N_NODES * F_OUT) / 256, 256, 0, stream>>>(outr, Sacc, Qacc, gamma, beta, bias, out);
    k_alpha  <<<N_EDGES / 256, 256, 0, stream>>>(ei, f1, f2, Mg, Dg, out);
}

// Round 4
// 118.361 us; speedup vs baseline: 1.3125x; 1.3125x over previous
//
#include <hip/hip_runtime.h>
#include <stdint.h>

// Problem constants (fixed by reference setup_inputs)
#define N_NODES 8192
#define F_IN    256
#define F_OUT   64
#define N_EDGES 262144
#define LEAKY   0.2f
#define BN_EPSF 1e-5f
#define WPR     256            // bitmap words per row = N_NODES/32
#define MAXDEG  256            // Poisson(32): max row degree ~66; 256 is 8-sigma safe
#define WT_LD   260            // Wt leading dim: 260%32==4 -> b128 reads at the 8-addr/bank floor
#define SLOTS   8              // BN accumulator slots (atomic contention split)

typedef unsigned int u32;

__device__ __forceinline__ float lrelu(float x) {
    return fmaxf(x, LEAKY * x);   // slope in (0,1): monotone increasing
}

// D1: bitmap zero (block-local slice) + Sacc/Qacc zero + hp/f1/f2.
// Zeroing is consumed only by LATER dispatches -> no intra-grid dependency.
// 256 blocks (1/CU), 4 waves x 8 rows.
__global__ __launch_bounds__(256) void k_pre(
    const float* __restrict__ h, const float* __restrict__ W, const float* __restrict__ a,
    float* __restrict__ hp, float* __restrict__ f1, float* __restrict__ f2,
    u32* __restrict__ bm, float* __restrict__ Sacc)
{
    __shared__ float Wt[F_OUT * WT_LD];   // 66,560 B (transposed, padded)
    __shared__ float hl[32 * F_IN];       // 32,768 B
    const int tid = threadIdx.x;

    // Zero this block's 32KB bitmap slice (float4 stores)
    {
        const float4 z = {0.f, 0.f, 0.f, 0.f};
        float4* dst = reinterpret_cast<float4*>(bm + (size_t)blockIdx.x * 8192);
#pragma unroll
        for (int p = 0; p < 8; ++p) dst[tid + p * 256] = z;
        if (blockIdx.x == 0)  // Sacc+Qacc = 2*SLOTS*64 floats = 256 float4
            reinterpret_cast<float4*>(Sacc)[tid] = z;
    }

    // Transpose W[k][o] -> Wt[o][k] with 8x8 tile mapping:
    // lane -> (o=obase+(lane&7), k=kbase+(lane>>3)); write bank = (4o+k)%32
    // covers all 32 banks 2-way -> conflict-free.
    const int w = tid >> 6, lane = tid & 63;
#pragma unroll
    for (int t = 0; t < 64; ++t) {
        const int T = t * 4 + w;                  // 256 tiles of 8x8
        const int o = (T & 7) * 8 + (lane & 7);
        const int k = (T >> 3) * 8 + (lane >> 3);
        Wt[o * WT_LD + k] = W[k * F_OUT + o];
    }

    // Stage 32 rows of h (float4 coalesced)
    const int row0 = blockIdx.x * 32;
    float4* hl4 = reinterpret_cast<float4*>(hl);
    const float4* h4 = reinterpret_cast<const float4*>(h + (size_t)row0 * F_IN);
#pragma unroll
    for (int p = 0; p < 8; ++p)
        hl4[tid + p * 256] = h4[tid + p * 256];
    __syncthreads();

    const int rbase = w * 8;                      // 8 rows per wave
    float acc[8] = {0.f, 0.f, 0.f, 0.f, 0.f, 0.f, 0.f, 0.f};
    const int o = lane;
    for (int q = 0; q < 64; ++q) {
        const float4 wv = *reinterpret_cast<const float4*>(&Wt[o * WT_LD + 4 * q]);
#pragma unroll
        for (int r = 0; r < 8; ++r) {
            const float4 hv = *reinterpret_cast<const float4*>(&hl[(rbase + r) * F_IN + 4 * q]);
            acc[r] += wv.x * hv.x + wv.y * hv.y + wv.z * hv.z + wv.w * hv.w;
        }
    }

    const float a1 = a[o], a2 = a[F_OUT + o];
#pragma unroll
    for (int r = 0; r < 8; ++r) {
        const int row = row0 + rbase + r;
        hp[row * F_OUT + o] = acc[r];
        float p1 = acc[r] * a1;
        float p2 = acc[r] * a2;
#pragma unroll
        for (int off = 32; off; off >>= 1) {
            p1 += __shfl_xor(p1, off, 64);
            p2 += __shfl_xor(p2, off, 64);
        }
        if (o == 0) { f1[row] = p1; f2[row] = p2; }
    }
}

// D2: adjacency bitmap (device-scope atomics dedup duplicate edges)
__global__ __launch_bounds__(256) void k_adj(const int* __restrict__ ei, u32* __restrict__ bm)
{
    const int e = blockIdx.x * 256 + threadIdx.x;
    const int r = ei[e];
    const int c = ei[N_EDGES + e];
    atomicOr(&bm[(size_t)r * WPR + (c >> 5)], 1u << (c & 31));
}

// D3: 1 wave per row (2048 blocks x 4 waves): bitmap -> per-wave neighbor list
// -> row max -> softmax denom + weighted hp gather (unroll-2), fused BN partials.
__global__ __launch_bounds__(256) void k_attn(
    const u32* __restrict__ bm, const float* __restrict__ hp,
    const float* __restrict__ f1g, const float* __restrict__ f2g,
    float* __restrict__ Mg, float* __restrict__ Dg, float* __restrict__ outr,
    float* __restrict__ Sacc, float* __restrict__ Qacc)
{
    __shared__ int   nbr[4][MAXDEG];   // 4 KB
    __shared__ float fv [4][MAXDEG];   // 4 KB
    __shared__ int   cnt[4];
    __shared__ float bnS[4][F_OUT], bnQ[4][F_OUT];
    const int tid = threadIdx.x;
    const int w = tid >> 6, lane = tid & 63;
    const int row = blockIdx.x * 4 + w;

    if (lane == 0) cnt[w] = 0;   // same-wave DS ordering: no barrier needed

    float mymax = -1e30f;
    const u32* bmrow = bm + (size_t)row * WPR;
#pragma unroll
    for (int r4 = 0; r4 < 4; ++r4) {
        const int widx = r4 * 64 + lane;
        u32 bits = bmrow[widx];
        if (bits) {
            int pos = atomicAdd(&cnt[w], __popc(bits));
            while (bits) {
                const int b = __ffs(bits) - 1;
                bits &= bits - 1;
                const int j = widx * 32 + b;
                const float v = f2g[j];
                mymax = fmaxf(mymax, v);
                if (pos < MAXDEG) { nbr[w][pos] = j; fv[w][pos] = v; }
                ++pos;
            }
        }
    }
#pragma unroll
    for (int off = 32; off; off >>= 1)
        mymax = fmaxf(mymax, __shfl_xor(mymax, off, 64));

    const int deg = min(cnt[w], MAXDEG);
    const float f1i = f1g[row];
    float M = lrelu(f1i + mymax);

    // unroll-2 with independent accumulators (shorter dependence chains)
    float den0 = 0.f, den1 = 0.f, acc0 = 0.f, acc1 = 0.f;
    int n = 0;
    for (; n + 2 <= deg; n += 2) {
        const int j0 = nbr[w][n],     j1 = nbr[w][n + 1];
        const float w0 = __expf(lrelu(f1i + fv[w][n]) - M);
        const float w1 = __expf(lrelu(f1i + fv[w][n + 1]) - M);
        den0 += w0;                      den1 += w1;
        acc0 += w0 * hp[j0 * F_OUT + lane];
        acc1 += w1 * hp[j1 * F_OUT + lane];
    }
    if (n < deg) {
        const int j0 = nbr[w][n];
        const float w0 = __expf(lrelu(f1i + fv[w][n]) - M);
        den0 += w0;
        acc0 += w0 * hp[j0 * F_OUT + lane];
    }
    float den = den0 + den1;
    float v = (acc0 + acc1) / den;
    if (deg == 0) { den = 1.f; M = 0.f; v = 0.f; }   // degenerate guard (P ~ e^-32)

    outr[row * F_OUT + lane] = v;
    if (lane == 0) { Mg[row] = M; Dg[row] = den; }

    // fused BN partials: block-level feature sums, one coalesced atomic per block
    bnS[w][lane] = v;
    bnQ[w][lane] = v * v;
    __syncthreads();
    if (w == 0) {
        const float s = bnS[0][lane] + bnS[1][lane] + bnS[2][lane] + bnS[3][lane];
        const float q = bnQ[0][lane] + bnQ[1][lane] + bnQ[2][lane] + bnQ[3][lane];
        const int slot = blockIdx.x & (SLOTS - 1);
        atomicAdd(&Sacc[slot * F_OUT + lane], s);
        atomicAdd(&Qacc[slot * F_OUT + lane], q);
    }
}

// D4: blocks [0,512) = BN finalize+apply (float4); blocks [512,1536) = alpha.
__global__ __launch_bounds__(256) void k_post(
    const float* __restrict__ outr, const float* __restrict__ Sacc,
    const float* __restrict__ Qacc, const float* __restrict__ gamma,
    const float* __restrict__ beta, const float* __restrict__ bias,
    const int* __restrict__ ei, const float* __restrict__ f1g,
    const float* __restrict__ f2g, const float* __restrict__ Mg,
    const float* __restrict__ Dg, float* __restrict__ out)
{
    const int tid = threadIdx.x;
    if (blockIdx.x < 512) {
        __shared__ float sm[F_OUT], sr[F_OUT], sg[F_OUT], sb[F_OUT];
        if (tid < F_OUT) {
            float s = 0.f, q = 0.f;
#pragma unroll
            for (int k = 0; k < SLOTS; ++k) {
                s += Sacc[k * F_OUT + tid];
                q += Qacc[k * F_OUT + tid];
            }
            const float mean = s * (1.f / N_NODES);
            const float var = q * (1.f / N_NODES) - mean * mean;
            sm[tid] = mean;
            sr[tid] = rsqrtf(var + BN_EPSF);
            sg[tid] = gamma[tid];
            sb[tid] = beta[tid] + bias[tid];
        }
        __syncthreads();
        const int gid = blockIdx.x * 256 + tid;          // float4 index
        const float4 ov = reinterpret_cast<const float4*>(outr)[gid];
        const int o0 = (gid & 15) * 4;
        float4 res;
        res.x = (ov.x - sm[o0 + 0]) * sr[o0 + 0] * sg[o0 + 0] + sb[o0 + 0];
        res.y = (ov.y - sm[o0 + 1]) * sr[o0 + 1] * sg[o0 + 1] + sb[o0 + 1];
        res.z = (ov.z - sm[o0 + 2]) * sr[o0 + 2] * sg[o0 + 2] + sb[o0 + 2];
        res.w = (ov.w - sm[o0 + 3]) * sr[o0 + 3] * sg[o0 + 3] + sb[o0 + 3];
        reinterpret_cast<float4*>(out)[gid] = res;
    } else {
        const int e = (blockIdx.x - 512) * 256 + tid;
        const int r = ei[e];
        const int c = ei[N_EDGES + e];
        out[N_NODES * F_OUT + e] = __expf(lrelu(f1g[r] + f2g[c]) - Mg[r]) / Dg[r];
    }
}

extern "C" void kernel_launch(void* const* d_in, const int* in_sizes, int n_in,
                              void* d_out, int out_size, void* d_ws, size_t ws_size,
                              hipStream_t stream) {
    const float* h     = (const float*)d_in[0];
    const int*   ei    = (const int*)  d_in[1];
    const float* W     = (const float*)d_in[2];
    const float* a     = (const float*)d_in[3];
    const float* bias  = (const float*)d_in[4];
    const float* gamma = (const float*)d_in[5];
    const float* beta  = (const float*)d_in[6];
    float* out = (float*)d_out;

    char* ws = (char*)d_ws;
    float* hp    = (float*)(ws + 0);          // 2 MB
    float* f1    = (float*)(ws + 2097152);    // 32 KB
    float* f2    = (float*)(ws + 2129920);    // 32 KB
    float* Mg    = (float*)(ws + 2162688);    // 32 KB
    float* Dg    = (float*)(ws + 2195456);    // 32 KB
    float* outr  = (float*)(ws + 2228224);    // 2 MB
    float* Sacc  = (float*)(ws + 4325376);    // 2 KB (8 slots x 64)
    float* Qacc  = (float*)(ws + 4327424);    // 2 KB
    u32*   bm    = (u32*)  (ws + 4329472);    // 8 MB
    if (ws_size < (size_t)4329472 + (size_t)N_NODES * WPR * 4) return;

    k_pre <<<256,  256, 0, stream>>>(h, W, a, hp, f1, f2, bm, Sacc);
    k_adj <<<N_EDGES / 256, 256, 0, stream>>>(ei, bm);
    k_attn<<<N_NODES / 4, 256, 0, stream>>>(bm, hp, f1, f2, Mg, Dg, outr, Sacc, Qacc);
    k_post<<<1536, 256, 0, stream>>>(outr, Sacc, Qacc, gamma, beta, bias,
                                     ei, f1, f2, Mg, Dg, out);
}